// Round 1
// baseline (4940.200 us; speedup 1.0000x reference)
//
#include <hip/hip_runtime.h>
#include <hip/hip_bf16.h>
#include <math.h>

// Problem constants
#define B_  256
#define T_  40
#define IN_ 2048
#define E_  512
#define H_  1024
#define V_  5000
#define G4_ 4096   // 4*H... careful: 4*H = 4096

__device__ __forceinline__ float sigm(float x) { return 1.0f / (1.0f + expf(-x)); }

// ---------------------------------------------------------------------------
// Generic tiled fp32 GEMM: C[M,N] = gather(A)[M,K] @ B[N,K]^T + bias[N]
//                                   + addMat[(row/rowDiv)*addStride + col]
// BM=BN=64, BK=16, 256 threads (16x16), 4x4 per thread.
// M must be a multiple of 64 (true for all call sites). N may be ragged.
// ---------------------------------------------------------------------------
__global__ __launch_bounds__(256) void gemm_bt(
    const float* __restrict__ A, int lda,
    const int* __restrict__ gidx,            // row gather for A, or nullptr
    const float* __restrict__ Bm, int ldb,
    const float* __restrict__ bias,          // [N] or nullptr
    const float* __restrict__ addMat,        // or nullptr
    int rowDiv, long long addStride,
    float* __restrict__ C, int ldc,
    int N, int K)
{
    const int BM = 64, BN = 64, BK = 16;
    __shared__ float As[BK][BM];
    __shared__ float Bs[BK][BN];

    const int tx = threadIdx.x, ty = threadIdx.y;
    const int tid = ty * 16 + tx;
    const int brow0 = blockIdx.y * BM;
    const int bcol0 = blockIdx.x * BN;

    // tile-load coordinates: each thread loads 4 consecutive K-elements
    const int e0   = tid * 4;
    const int la_r = e0 / BK;      // 0..63
    const int la_k = e0 % BK;      // 0,4,8,12

    long long arow_base;
    {
        int gr = brow0 + la_r;                 // global A row (logical)
        int ar = gidx ? gidx[gr] : gr;         // gathered physical row
        arow_base = (long long)ar * lda;
    }
    const int bRowG = bcol0 + la_r;
    const bool bValid = (bRowG < N);
    const long long brow_base = (long long)bRowG * ldb;

    float acc[4][4] = {};

    for (int k0 = 0; k0 < K; k0 += BK) {
        float4 av = *(const float4*)(A + arow_base + k0 + la_k);
        float4 bv = make_float4(0.f, 0.f, 0.f, 0.f);
        if (bValid) bv = *(const float4*)(Bm + brow_base + k0 + la_k);

        As[la_k + 0][la_r] = av.x;
        As[la_k + 1][la_r] = av.y;
        As[la_k + 2][la_r] = av.z;
        As[la_k + 3][la_r] = av.w;
        Bs[la_k + 0][la_r] = bv.x;
        Bs[la_k + 1][la_r] = bv.y;
        Bs[la_k + 2][la_r] = bv.z;
        Bs[la_k + 3][la_r] = bv.w;
        __syncthreads();

        #pragma unroll
        for (int kk = 0; kk < BK; ++kk) {
            float af[4], bf[4];
            #pragma unroll
            for (int i = 0; i < 4; ++i) af[i] = As[kk][ty * 4 + i];
            #pragma unroll
            for (int j = 0; j < 4; ++j) bf[j] = Bs[kk][tx * 4 + j];
            #pragma unroll
            for (int i = 0; i < 4; ++i)
                #pragma unroll
                for (int j = 0; j < 4; ++j)
                    acc[i][j] = fmaf(af[i], bf[j], acc[i][j]);
        }
        __syncthreads();
    }

    // epilogue
    #pragma unroll
    for (int i = 0; i < 4; ++i) {
        const int row = brow0 + ty * 4 + i;
        const float* addRow = addMat ? (addMat + (long long)(row / rowDiv) * addStride)
                                     : nullptr;
        #pragma unroll
        for (int j = 0; j < 4; ++j) {
            const int col = bcol0 + tx * 4 + j;
            if (col < N) {
                float v = acc[i][j];
                if (bias)   v += bias[col];
                if (addRow) v += addRow[col];
                C[(long long)row * ldc + col] = v;
            }
        }
    }
}

// ---------------------------------------------------------------------------
// Prep kernel: embedding-gather row indices (shifted labels), logits gather
// indices, and combined bias b_ih + b_hh.
// ---------------------------------------------------------------------------
__global__ void prep_kernel(const int* __restrict__ labels,   // [B,T]
                            const float* __restrict__ b_ih,
                            const float* __restrict__ b_hh,
                            int* __restrict__ idxEmb,          // [B*T]
                            int* __restrict__ idxLog,          // [B*T]
                            float* __restrict__ bsum)          // [4H]
{
    int r = blockIdx.x * blockDim.x + threadIdx.x;
    if (r < B_ * T_) {
        int b = r / T_, t = r % T_;
        int tsrc = (t == 0) ? (T_ - 1) : (t - 1);
        idxEmb[r] = labels[b * T_ + tsrc];
        idxLog[r] = t * B_ + b;
    }
    if (r < G4_) bsum[r] = b_ih[r] + b_hh[r];
}

// ---------------------------------------------------------------------------
// LSTM pointwise cell: g[B,4H] (i,f,g,o torch order) + c -> c', h'
// ---------------------------------------------------------------------------
__global__ __launch_bounds__(256) void lstm_cell(const float* __restrict__ g,
                                                 float* __restrict__ c,
                                                 float* __restrict__ h_out)
{
    int tid = blockIdx.x * blockDim.x + threadIdx.x;
    if (tid >= B_ * H_) return;
    int b = tid / H_, k = tid % H_;
    const float* gb = g + (long long)b * G4_;
    float gi = gb[k];
    float gf = gb[H_ + k];
    float gg = gb[2 * H_ + k];
    float go = gb[3 * H_ + k];
    float cc = sigm(gf) * c[tid] + sigm(gi) * tanhf(gg);
    c[tid] = cc;
    h_out[tid] = sigm(go) * tanhf(cc);
}

extern "C" void kernel_launch(void* const* d_in, const int* in_sizes, int n_in,
                              void* d_out, int out_size, void* d_ws, size_t ws_size,
                              hipStream_t stream)
{
    const float* X      = (const float*)d_in[0];
    const int*   labels = (const int*)  d_in[1];
    const float* W_f    = (const float*)d_in[2];
    const float* b_f    = (const float*)d_in[3];
    const float* emb    = (const float*)d_in[4];
    const float* W_ih   = (const float*)d_in[5];
    const float* W_hh   = (const float*)d_in[6];
    const float* b_ih   = (const float*)d_in[7];
    const float* b_hh   = (const float*)d_in[8];
    const float* W_out  = (const float*)d_in[9];
    const float* b_out  = (const float*)d_in[10];
    float* out = (float*)d_out;
    (void)in_sizes; (void)n_in; (void)out_size; (void)ws_size;

    // ---- workspace layout (256B aligned chunks) ----
    char* ws = (char*)d_ws;
    size_t off = 0;
    auto alloc = [&](size_t bytes) {
        void* p = ws + off;
        off += (bytes + 255) & ~(size_t)255;
        return p;
    };
    float* features = (float*)alloc(B_ * E_  * 4);        // [256,512]
    float* baseMat  = (float*)alloc(B_ * G4_ * 4);        // [256,4096]
    float* hs       = (float*)alloc((size_t)T_ * B_ * H_ * 4); // [40,256,1024]
    float* gbuf     = (float*)alloc(B_ * G4_ * 4);        // [256,4096]
    float* cbuf     = (float*)alloc(B_ * H_  * 4);        // [256,1024]
    float* zbuf     = (float*)alloc(B_ * H_  * 4);        // zeros (h0)
    float* bsum     = (float*)alloc(G4_ * 4);
    int*   idxEmb   = (int*)  alloc(B_ * T_ * 4);
    int*   idxLog   = (int*)  alloc(B_ * T_ * 4);

    // gates_x [B*T, 4H] lives in d_out (41.94M floats <= 51.2M) --
    // consumed before the logits GEMM overwrites d_out.
    float* gates = out;

    // ---- zero init for c and h0 ----
    hipMemsetAsync(cbuf, 0, B_ * H_ * 4, stream);
    hipMemsetAsync(zbuf, 0, B_ * H_ * 4, stream);

    // ---- prep ----
    prep_kernel<<<(B_ * T_ + 255) / 256, 256, 0, stream>>>(
        labels, b_ih, b_hh, idxEmb, idxLog, bsum);

    dim3 thr(16, 16);

    // features = X @ W_f^T + b_f            [256,512] K=2048
    gemm_bt<<<dim3(E_ / 64, B_ / 64), thr, 0, stream>>>(
        X, IN_, nullptr, W_f, IN_, b_f,
        nullptr, 1, 0, features, E_, E_, IN_);

    // base = features @ W_ih[:, :E]^T + (b_ih + b_hh)   [256,4096] K=512
    gemm_bt<<<dim3(G4_ / 64, B_ / 64), thr, 0, stream>>>(
        features, E_, nullptr, W_ih, 2 * E_, bsum,
        nullptr, 1, 0, baseMat, G4_, G4_, E_);

    // gates = gather(emb) @ W_ih[:, E:]^T + base[row/T]   [10240,4096] K=512
    gemm_bt<<<dim3(G4_ / 64, (B_ * T_) / 64), thr, 0, stream>>>(
        emb, E_, idxEmb, W_ih + E_, 2 * E_, nullptr,
        baseMat, T_, G4_, gates, G4_, G4_, E_);

    // ---- recurrence ----
    for (int t = 0; t < T_; ++t) {
        const float* hprev = (t == 0) ? zbuf : (hs + (size_t)(t - 1) * B_ * H_);
        // g = hprev @ W_hh^T + gates[:, t, :]   [256,4096] K=1024
        gemm_bt<<<dim3(G4_ / 64, B_ / 64), thr, 0, stream>>>(
            hprev, H_, nullptr, W_hh, H_, nullptr,
            gates + (size_t)t * G4_, 1, (long long)T_ * G4_,
            gbuf, G4_, G4_, H_);
        // cell update -> c, hs[t]
        lstm_cell<<<(B_ * H_ + 255) / 256, 256, 0, stream>>>(
            gbuf, cbuf, hs + (size_t)t * B_ * H_);
    }

    // logits = gather(hs) @ W_out^T + b_out   [10240,5000] K=1024
    gemm_bt<<<dim3((V_ + 63) / 64, (B_ * T_) / 64), thr, 0, stream>>>(
        hs, H_, idxLog, W_out, H_, b_out,
        nullptr, 1, 0, out, V_, V_, H_);
}

// Round 2
// 2283.180 us; speedup vs baseline: 2.1637x; 2.1637x over previous
//
#include <hip/hip_runtime.h>
#include <hip/hip_bf16.h>
#include <math.h>

#define B_  256
#define T_  40
#define IN_ 2048
#define E_  512
#define H_  1024
#define V_  5000
#define G4_ 4096   // 4*H

typedef __bf16 bf16x8 __attribute__((ext_vector_type(8)));
typedef float  f32x4  __attribute__((ext_vector_type(4)));

__device__ __forceinline__ float sigm(float x) { return 1.0f / (1.0f + expf(-x)); }

__device__ __forceinline__ unsigned short f2b(float x) {
    __hip_bfloat16 h = __float2bfloat16(x);
    return *reinterpret_cast<unsigned short*>(&h);
}

#define GLOAD_LDS(g, l) __builtin_amdgcn_global_load_lds(                     \
    (const __attribute__((address_space(1))) unsigned int*)(g),               \
    (__attribute__((address_space(3))) unsigned int*)(l), 16, 0, 0)

// ---------------------------------------------------------------------------
// bf16 MFMA GEMM: C[M,N](f32) = gather(A)[M,K](bf16) @ B[N,K](bf16)^T
//                               + bias[N] + addMat[(row/rowDiv)*addStride+col]
// 128x128 tile, BK=32, 256 threads = 4 waves (2x2), 16x16x32 MFMA, 4x4 frags.
// M % 128 == 0. B must be padded to ceil(N/128)*128 rows. Cols guarded by N.
// ---------------------------------------------------------------------------
__global__ __launch_bounds__(256) void gemm_mfma(
    const unsigned short* __restrict__ A, int lda,
    const int* __restrict__ gidx,
    const unsigned short* __restrict__ Bm, int ldb,
    const float* __restrict__ bias,
    const float* __restrict__ addMat, int rowDiv, long long addStride,
    float* __restrict__ C, int ldc, int N, int K)
{
    __shared__ unsigned short As[128 * 32];
    __shared__ unsigned short Bs[128 * 32];

    const int tid  = threadIdx.x;
    const int wave = tid >> 6, lane = tid & 63;
    const int brow0 = blockIdx.y * 128, bcol0 = blockIdx.x * 128;
    const int wrow0 = (wave >> 1) * 64, wcol0 = (wave & 1) * 64;

    // staging: each wave fills 2 A-segments + 2 B-segments of 16 rows x 32 cols
    const int srow = lane >> 2;            // row within segment
    const int scol = (lane & 3) * 8;       // starting col element (16B)
    const unsigned short* pA[2];
    const unsigned short* pB[2];
    unsigned short* lA[2];
    unsigned short* lB[2];
    #pragma unroll
    for (int i = 0; i < 2; ++i) {
        int seg = wave * 2 + i;
        int row = seg * 16 + srow;
        long long ar = gidx ? (long long)gidx[brow0 + row] : (long long)(brow0 + row);
        pA[i] = A + ar * lda + scol;
        pB[i] = Bm + (long long)(bcol0 + row) * ldb + scol;
        lA[i] = &As[seg * 16 * 32];
        lB[i] = &Bs[seg * 16 * 32];
    }

    f32x4 acc[4][4] = {};
    const int foff = (lane & 15) * 32 + (lane >> 4) * 8;  // per-lane frag offset

    for (int k0 = 0; k0 < K; k0 += 32) {
        GLOAD_LDS(pA[0] + k0, lA[0]);
        GLOAD_LDS(pA[1] + k0, lA[1]);
        GLOAD_LDS(pB[0] + k0, lB[0]);
        GLOAD_LDS(pB[1] + k0, lB[1]);
        __syncthreads();

        bf16x8 a[4], b[4];
        #pragma unroll
        for (int m = 0; m < 4; ++m)
            a[m] = *(const bf16x8*)&As[(wrow0 + m * 16) * 32 + foff];
        #pragma unroll
        for (int n = 0; n < 4; ++n)
            b[n] = *(const bf16x8*)&Bs[(wcol0 + n * 16) * 32 + foff];
        #pragma unroll
        for (int m = 0; m < 4; ++m)
            #pragma unroll
            for (int n = 0; n < 4; ++n)
                acc[m][n] = __builtin_amdgcn_mfma_f32_16x16x32_bf16(
                    a[m], b[n], acc[m][n], 0, 0, 0);
        __syncthreads();
    }

    // epilogue: C/D layout col = lane&15, row = (lane>>4)*4 + reg
    #pragma unroll
    for (int m = 0; m < 4; ++m) {
        #pragma unroll
        for (int j = 0; j < 4; ++j) {
            int row = brow0 + wrow0 + m * 16 + (lane >> 4) * 4 + j;
            const float* addRow = addMat
                ? addMat + (long long)(row / rowDiv) * addStride : nullptr;
            #pragma unroll
            for (int n = 0; n < 4; ++n) {
                int col = bcol0 + wcol0 + n * 16 + (lane & 15);
                if (col < N) {
                    float v = acc[m][n][j];
                    if (bias)   v += bias[col];
                    if (addRow) v += addRow[col];
                    C[(long long)row * ldc + col] = v;
                }
            }
        }
    }
}

// ---------------------------------------------------------------------------
// fp32 tiled GEMM (kept for the two small GEMMs): C = A @ B^T + bias
// ---------------------------------------------------------------------------
__global__ __launch_bounds__(256) void gemm_bt(
    const float* __restrict__ A, int lda,
    const float* __restrict__ Bm, int ldb,
    const float* __restrict__ bias,
    float* __restrict__ C, int ldc, int N, int K)
{
    const int BK = 16;
    __shared__ float As[BK][64];
    __shared__ float Bs[BK][64];

    const int tx = threadIdx.x, ty = threadIdx.y;
    const int tid = ty * 16 + tx;
    const int brow0 = blockIdx.y * 64;
    const int bcol0 = blockIdx.x * 64;

    const int e0   = tid * 4;
    const int la_r = e0 / BK;
    const int la_k = e0 % BK;

    const long long arow_base = (long long)(brow0 + la_r) * lda;
    const int bRowG = bcol0 + la_r;
    const bool bValid = (bRowG < N);
    const long long brow_base = (long long)bRowG * ldb;

    float acc[4][4] = {};

    for (int k0 = 0; k0 < K; k0 += BK) {
        float4 av = *(const float4*)(A + arow_base + k0 + la_k);
        float4 bv = make_float4(0.f, 0.f, 0.f, 0.f);
        if (bValid) bv = *(const float4*)(Bm + brow_base + k0 + la_k);

        As[la_k + 0][la_r] = av.x; As[la_k + 1][la_r] = av.y;
        As[la_k + 2][la_r] = av.z; As[la_k + 3][la_r] = av.w;
        Bs[la_k + 0][la_r] = bv.x; Bs[la_k + 1][la_r] = bv.y;
        Bs[la_k + 2][la_r] = bv.z; Bs[la_k + 3][la_r] = bv.w;
        __syncthreads();

        #pragma unroll
        for (int kk = 0; kk < BK; ++kk) {
            float af[4], bf[4];
            #pragma unroll
            for (int i = 0; i < 4; ++i) af[i] = As[kk][ty * 4 + i];
            #pragma unroll
            for (int j = 0; j < 4; ++j) bf[j] = Bs[kk][tx * 4 + j];
            #pragma unroll
            for (int i = 0; i < 4; ++i)
                #pragma unroll
                for (int j = 0; j < 4; ++j)
                    acc[i][j] = fmaf(af[i], bf[j], acc[i][j]);
        }
        __syncthreads();
    }

    #pragma unroll
    for (int i = 0; i < 4; ++i) {
        const int row = brow0 + ty * 4 + i;
        #pragma unroll
        for (int j = 0; j < 4; ++j) {
            const int col = bcol0 + tx * 4 + j;
            if (col < N) {
                float v = acc[i][j];
                if (bias) v += bias[col];
                C[(long long)row * ldc + col] = v;
            }
        }
    }
}

// ---------------------------------------------------------------------------
// f32 -> bf16 conversion with optional column slice + zero row padding
// ---------------------------------------------------------------------------
__global__ void conv2bf(const float* __restrict__ src, unsigned short* __restrict__ dst,
                        int rows, int rowsPad, int cols, int srcld, int srccol0)
{
    int i = blockIdx.x * blockDim.x + threadIdx.x;
    int c4n = cols >> 2;
    if (i >= rowsPad * c4n) return;
    int r = i / c4n, c4 = i % c4n;
    ushort4 o;
    if (r < rows) {
        float4 v = *(const float4*)(src + (long long)r * srcld + srccol0 + c4 * 4);
        o.x = f2b(v.x); o.y = f2b(v.y); o.z = f2b(v.z); o.w = f2b(v.w);
    } else {
        o = make_ushort4(0, 0, 0, 0);
    }
    *(ushort4*)(dst + (long long)r * cols + c4 * 4) = o;
}

// ---------------------------------------------------------------------------
// prep: gather indices + combined bias
// ---------------------------------------------------------------------------
__global__ void prep_kernel(const int* __restrict__ labels,
                            const float* __restrict__ b_ih,
                            const float* __restrict__ b_hh,
                            int* __restrict__ idxEmb,
                            int* __restrict__ idxLog,
                            float* __restrict__ bsum)
{
    int r = blockIdx.x * blockDim.x + threadIdx.x;
    if (r < B_ * T_) {
        int b = r / T_, t = r % T_;
        int tsrc = (t == 0) ? (T_ - 1) : (t - 1);
        idxEmb[r] = labels[b * T_ + tsrc];
        idxLog[r] = (t + 1) * B_ + b;   // hs_bf slot t+1 holds h_t
    }
    if (r < G4_) bsum[r] = b_ih[r] + b_hh[r];
}

// ---------------------------------------------------------------------------
// LSTM pointwise cell: g[B,4H] + c -> c'(f32), h'(bf16)
// ---------------------------------------------------------------------------
__global__ __launch_bounds__(256) void lstm_cell(const float* __restrict__ g,
                                                 float* __restrict__ c,
                                                 unsigned short* __restrict__ h_out)
{
    int tid = blockIdx.x * blockDim.x + threadIdx.x;
    if (tid >= B_ * H_) return;
    int b = tid / H_, k = tid % H_;
    const float* gb = g + (long long)b * G4_;
    float gi = gb[k];
    float gf = gb[H_ + k];
    float gg = gb[2 * H_ + k];
    float go = gb[3 * H_ + k];
    float cc = sigm(gf) * c[tid] + sigm(gi) * tanhf(gg);
    c[tid] = cc;
    h_out[tid] = f2b(sigm(go) * tanhf(cc));
}

extern "C" void kernel_launch(void* const* d_in, const int* in_sizes, int n_in,
                              void* d_out, int out_size, void* d_ws, size_t ws_size,
                              hipStream_t stream)
{
    const float* X      = (const float*)d_in[0];
    const int*   labels = (const int*)  d_in[1];
    const float* W_f    = (const float*)d_in[2];
    const float* b_f    = (const float*)d_in[3];
    const float* emb    = (const float*)d_in[4];
    const float* W_ih   = (const float*)d_in[5];
    const float* W_hh   = (const float*)d_in[6];
    const float* b_ih   = (const float*)d_in[7];
    const float* b_hh   = (const float*)d_in[8];
    const float* W_out  = (const float*)d_in[9];
    const float* b_out  = (const float*)d_in[10];
    float* out = (float*)d_out;
    (void)in_sizes; (void)n_in; (void)out_size; (void)ws_size;

    // ---- workspace layout ----
    char* ws = (char*)d_ws;
    size_t off = 0;
    auto alloc = [&](size_t bytes) {
        void* p = ws + off;
        off += (bytes + 255) & ~(size_t)255;
        return p;
    };
    unsigned short* emb_bf  = (unsigned short*)alloc((size_t)(V_ + 1) * E_ * 2);
    unsigned short* WihE_bf = (unsigned short*)alloc((size_t)G4_ * E_ * 2);
    unsigned short* Whh_bf  = (unsigned short*)alloc((size_t)G4_ * H_ * 2);
    unsigned short* Wout_bf = (unsigned short*)alloc((size_t)5120 * H_ * 2);
    unsigned short* hs_bf   = (unsigned short*)alloc((size_t)(T_ + 1) * B_ * H_ * 2);
    float* features = (float*)alloc(B_ * E_ * 4);
    float* cbuf     = (float*)alloc(B_ * H_ * 4);
    float* bsum     = (float*)alloc(G4_ * 4);
    int*   idxEmb   = (int*)  alloc(B_ * T_ * 4);
    int*   idxLog   = (int*)  alloc(B_ * T_ * 4);

    // d_out reuse: gates [B*T,4H] at front (consumed before logits GEMM);
    // baseMat + gbuf in the tail beyond the gates region.
    float* gates   = out;
    float* baseMat = out + (size_t)B_ * T_ * G4_;               // 1M floats
    float* gbuf    = baseMat + (size_t)B_ * G4_;                 // 1M floats

    hipMemsetAsync(cbuf, 0, B_ * H_ * 4, stream);
    hipMemsetAsync(hs_bf, 0, B_ * H_ * 2, stream);               // h0 = 0 (slot 0)

    prep_kernel<<<(B_ * T_ + 255) / 256, 256, 0, stream>>>(
        labels, b_ih, b_hh, idxEmb, idxLog, bsum);

    // ---- weight conversions to bf16 ----
    {
        int n;
        n = (V_ + 1) * E_ / 4;
        conv2bf<<<(n + 255) / 256, 256, 0, stream>>>(emb, emb_bf, V_ + 1, V_ + 1, E_, E_, 0);
        n = G4_ * E_ / 4;
        conv2bf<<<(n + 255) / 256, 256, 0, stream>>>(W_ih, WihE_bf, G4_, G4_, E_, 2 * E_, E_);
        n = G4_ * H_ / 4;
        conv2bf<<<(n + 255) / 256, 256, 0, stream>>>(W_hh, Whh_bf, G4_, G4_, H_, H_, 0);
        n = 5120 * H_ / 4;
        conv2bf<<<(n + 255) / 256, 256, 0, stream>>>(W_out, Wout_bf, V_, 5120, H_, H_, 0);
    }

    dim3 thr(16, 16);

    // features = X @ W_f^T + b_f          [256,512] K=2048 (fp32)
    gemm_bt<<<dim3(E_ / 64, B_ / 64), thr, 0, stream>>>(
        X, IN_, W_f, IN_, b_f, features, E_, E_, IN_);

    // base = features @ W_ih[:, :E]^T + (b_ih + b_hh)   [256,4096] K=512 (fp32)
    gemm_bt<<<dim3(G4_ / 64, B_ / 64), thr, 0, stream>>>(
        features, E_, W_ih, 2 * E_, bsum, baseMat, G4_, G4_, E_);

    // gates = gather(emb_bf) @ WihE^T + base[row/T]   [10240,4096] K=512 (MFMA)
    gemm_mfma<<<dim3(G4_ / 128, (B_ * T_) / 128), 256, 0, stream>>>(
        emb_bf, E_, idxEmb, WihE_bf, E_, nullptr,
        baseMat, T_, G4_, gates, G4_, G4_, E_);

    // ---- recurrence ----
    for (int t = 0; t < T_; ++t) {
        // g = h_{t-1} @ W_hh^T + gates[:,t,:]   [256,4096] K=1024 (MFMA)
        gemm_mfma<<<dim3(G4_ / 128, B_ / 128), 256, 0, stream>>>(
            hs_bf + (size_t)t * B_ * H_, H_, nullptr, Whh_bf, H_, nullptr,
            gates + (size_t)t * G4_, 1, (long long)T_ * G4_,
            gbuf, G4_, G4_, H_);
        lstm_cell<<<(B_ * H_ + 255) / 256, 256, 0, stream>>>(
            gbuf, cbuf, hs_bf + (size_t)(t + 1) * B_ * H_);
    }

    // logits = gather(hs_bf) @ W_out^T + b_out   [10240,5000] K=1024 (MFMA)
    gemm_mfma<<<dim3(5120 / 128, (B_ * T_) / 128), 256, 0, stream>>>(
        hs_bf, H_, idxLog, Wout_bf, H_, b_out,
        nullptr, 1, 0, out, V_, V_, H_);
}